// Round 1
// baseline (6404.169 us; speedup 1.0000x reference)
//
#include <hip/hip_runtime.h>
#include <hip/hip_bf16.h>

#define D 128
#define EPS 1e-8f

// ---------------- K1: row-normalize H -> Hn ----------------
// block 256 = 4 rows x 64 lanes; each lane owns 2 consecutive floats (float2)
__global__ void k_normalize(const float* __restrict__ H, float* __restrict__ Hn, int N) {
    int row = blockIdx.x * 4 + (threadIdx.x >> 6);
    int lane = threadIdx.x & 63;
    if (row >= N) return;
    float2 v = reinterpret_cast<const float2*>(H + (size_t)row * D)[lane];
    float ss = v.x * v.x + v.y * v.y;
    #pragma unroll
    for (int off = 32; off; off >>= 1) ss += __shfl_xor(ss, off, 64);
    float scale = 1.0f / (sqrtf(ss) + EPS);
    reinterpret_cast<float2*>(Hn + (size_t)row * D)[lane] =
        make_float2(v.x * scale, v.y * scale);
}

// ---------------- K2/K4: fp32 GEMM [N x 128] @ [128 x 128] -> [N x 128] ----------------
// block 256, output tile 64 rows x 128 cols. Thread: 8 rows x 4 cols.
__global__ void k_gemm128(const float* __restrict__ A, const float* __restrict__ B,
                          float* __restrict__ out, int N) {
    __shared__ float As[64][40];     // KT=32, padded stride 40 (16B aligned, bank-safe)
    __shared__ float Bs[32][128];
    int r0 = blockIdx.x * 64;
    int t = threadIdx.x;
    int c4 = (t & 31) * 4;
    int r8 = (t >> 5) * 8;
    float acc[8][4] = {};
    for (int k0 = 0; k0 < 128; k0 += 32) {
        __syncthreads();
        // A tile: 64x32 = 2048 floats = 512 float4, 2/thread
        #pragma unroll
        for (int q = 0; q < 2; ++q) {
            int idx = t * 2 + q;          // 0..511
            int rr = idx >> 3;            // 0..63
            int kk = (idx & 7) * 4;
            int grow = r0 + rr;
            float4 av = (grow < N)
                ? *reinterpret_cast<const float4*>(A + (size_t)grow * 128 + k0 + kk)
                : make_float4(0.f, 0.f, 0.f, 0.f);
            *reinterpret_cast<float4*>(&As[rr][kk]) = av;
        }
        // B tile: 32x128 = 4096 floats = 1024 float4, 4/thread
        #pragma unroll
        for (int q = 0; q < 4; ++q) {
            int idx = q * 256 + t;        // 0..1023
            int kk = idx >> 5;            // 0..31
            int cc = (idx & 31) * 4;
            *reinterpret_cast<float4*>(&Bs[kk][cc]) =
                *reinterpret_cast<const float4*>(B + (size_t)(k0 + kk) * 128 + cc);
        }
        __syncthreads();
        #pragma unroll 8
        for (int k = 0; k < 32; ++k) {
            float4 bv = *reinterpret_cast<const float4*>(&Bs[k][c4]);
            #pragma unroll
            for (int i = 0; i < 8; ++i) {
                float a = As[r8 + i][k];
                acc[i][0] += a * bv.x;
                acc[i][1] += a * bv.y;
                acc[i][2] += a * bv.z;
                acc[i][3] += a * bv.w;
            }
        }
    }
    #pragma unroll
    for (int i = 0; i < 8; ++i) {
        int grow = r0 + r8 + i;
        if (grow < N)
            *reinterpret_cast<float4*>(out + (size_t)grow * 128 + c4) =
                make_float4(acc[i][0], acc[i][1], acc[i][2], acc[i][3]);
    }
}

// ---------------- K3 (hot): per-edge mlp1 layer2 + scatter-add into C ----------------
// 32 edges per block, 256 threads.
// e1 = relu(P[src] + Q[dst] + b1_1)  staged in LDS [32][133]
// y  = relu(e1 @ W1_2 + b1_2); atomicAdd C[src] += y
__global__ void k_edge_mlp1(const int* __restrict__ src, const int* __restrict__ dst,
                            const float* __restrict__ P, const float* __restrict__ Q,
                            const float* __restrict__ b1_1, const float* __restrict__ W12,
                            const float* __restrict__ b1_2, float* __restrict__ C, int E) {
    __shared__ float e1[32][133];    // stride 133 (mod32=5, coprime) -> conflict-free col reads
    __shared__ float Ws[64][128];
    __shared__ int ssrc[32], sdst[32];
    int t = threadIdx.x;
    int e0 = blockIdx.x * 32;
    if (t < 32) {
        int ge = min(e0 + t, E - 1);
        ssrc[t] = src[ge];
        sdst[t] = dst[ge];
    }
    __syncthreads();
    // stage e1: thread t -> edge (t>>3), 16 consecutive feats at d0=(t&7)*16
    {
        int es = t >> 3;
        int d0 = (t & 7) * 16;
        const float4* Pp = reinterpret_cast<const float4*>(P + (size_t)ssrc[es] * 128 + d0);
        const float4* Qp = reinterpret_cast<const float4*>(Q + (size_t)sdst[es] * 128 + d0);
        const float4* bp = reinterpret_cast<const float4*>(b1_1 + d0);
        #pragma unroll
        for (int q = 0; q < 4; ++q) {
            float4 pv = Pp[q], qv = Qp[q], bv = bp[q];
            int dd = d0 + q * 4;
            e1[es][dd + 0] = fmaxf(pv.x + qv.x + bv.x, 0.f);
            e1[es][dd + 1] = fmaxf(pv.y + qv.y + bv.y, 0.f);
            e1[es][dd + 2] = fmaxf(pv.z + qv.z + bv.z, 0.f);
            e1[es][dd + 3] = fmaxf(pv.w + qv.w + bv.w, 0.f);
        }
    }
    // compute mapping: edge ec = t&31, 16 feats at f0=(t>>5)*16
    int ec = t & 31;
    int f0 = (t >> 5) * 16;
    float acc[16];
    {
        const float4* b4 = reinterpret_cast<const float4*>(b1_2 + f0);
        #pragma unroll
        for (int q = 0; q < 4; ++q) {
            float4 bv = b4[q];
            acc[q * 4 + 0] = bv.x; acc[q * 4 + 1] = bv.y;
            acc[q * 4 + 2] = bv.z; acc[q * 4 + 3] = bv.w;
        }
    }
    for (int k0 = 0; k0 < 128; k0 += 64) {
        __syncthreads();
        // load W1_2 K-tile [64][128]: 2048 float4, 8/thread
        #pragma unroll
        for (int q = 0; q < 8; ++q) {
            int idx = q * 256 + t;        // 0..2047
            int kk = idx >> 5;            // 0..63
            int cc = (idx & 31) * 4;
            *reinterpret_cast<float4*>(&Ws[kk][cc]) =
                *reinterpret_cast<const float4*>(W12 + (size_t)(k0 + kk) * 128 + cc);
        }
        __syncthreads();
        #pragma unroll 4
        for (int k = 0; k < 64; ++k) {
            float xv = e1[ec][k0 + k];
            const float4* wr = reinterpret_cast<const float4*>(&Ws[k][f0]);
            float4 w0 = wr[0], w1 = wr[1], w2 = wr[2], w3 = wr[3];
            acc[0]  += xv * w0.x; acc[1]  += xv * w0.y; acc[2]  += xv * w0.z; acc[3]  += xv * w0.w;
            acc[4]  += xv * w1.x; acc[5]  += xv * w1.y; acc[6]  += xv * w1.z; acc[7]  += xv * w1.w;
            acc[8]  += xv * w2.x; acc[9]  += xv * w2.y; acc[10] += xv * w2.z; acc[11] += xv * w2.w;
            acc[12] += xv * w3.x; acc[13] += xv * w3.y; acc[14] += xv * w3.z; acc[15] += xv * w3.w;
        }
    }
    int ge = e0 + ec;
    if (ge < E) {
        float* Crow = C + (size_t)ssrc[ec] * 128 + f0;
        #pragma unroll
        for (int j = 0; j < 16; ++j) {
            float y = fmaxf(acc[j], 0.f);
            atomicAdd(Crow + j, y);
        }
    }
}

// ---------------- K5: per-edge curvature + damped message + scatter ----------------
// one 64-lane wave per edge; block 256 = 4 edges
__global__ void k_edge_curv(const int* __restrict__ src, const int* __restrict__ dst,
                            const float* __restrict__ Hn,
                            const float* __restrict__ R, const float* __restrict__ T,
                            const float* __restrict__ b2_1, const float* __restrict__ w2_2,
                            const float* __restrict__ b2_2,
                            float* __restrict__ S, float* __restrict__ cnt, int E) {
    int e = blockIdx.x * 4 + (threadIdx.x >> 6);
    int lane = threadIdx.x & 63;
    if (e >= E) return;
    int si = src[e], dj = dst[e];
    float2 hi = reinterpret_cast<const float2*>(Hn + (size_t)si * 128)[lane];
    float2 hj = reinterpret_cast<const float2*>(Hn + (size_t)dj * 128)[lane];
    float cosp = hi.x * hj.x + hi.y * hj.y;
    float2 rv = reinterpret_cast<const float2*>(R + (size_t)si * 128)[lane];
    float2 tv = reinterpret_cast<const float2*>(T + (size_t)dj * 128)[lane];
    float2 bv = reinterpret_cast<const float2*>(b2_1)[lane];
    float2 wv = reinterpret_cast<const float2*>(w2_2)[lane];
    float g0 = fmaxf(rv.x + tv.x + bv.x, 0.f);
    float g1 = fmaxf(rv.y + tv.y + bv.y, 0.f);
    float cur = g0 * wv.x + g1 * wv.y;
    #pragma unroll
    for (int off = 32; off; off >>= 1) {
        cosp += __shfl_xor(cosp, off, 64);
        cur  += __shfl_xor(cur, off, 64);
    }
    cur += b2_2[0];
    float hex = cur * (hj.x - cosp * hi.x);
    float hey = cur * (hj.y - cosp * hi.y);
    float* Srow = S + (size_t)si * 128 + lane * 2;
    atomicAdd(Srow + 0, hex);
    atomicAdd(Srow + 1, hey);
    if (lane == 0) atomicAdd(cnt + si, 1.0f);
}

// ---------------- K6: mean + row-normalize -> out ----------------
__global__ void k_finalize(const float* __restrict__ S, const float* __restrict__ cnt,
                           float* __restrict__ out, int N) {
    int row = blockIdx.x * 4 + (threadIdx.x >> 6);
    int lane = threadIdx.x & 63;
    if (row >= N) return;
    float inv = 1.0f / fmaxf(cnt[row], 1.0f);
    float2 v = reinterpret_cast<const float2*>(S + (size_t)row * 128)[lane];
    v.x *= inv; v.y *= inv;
    float ss = v.x * v.x + v.y * v.y;
    #pragma unroll
    for (int off = 32; off; off >>= 1) ss += __shfl_xor(ss, off, 64);
    float scale = 1.0f / (sqrtf(ss) + EPS);
    reinterpret_cast<float2*>(out + (size_t)row * 128)[lane] =
        make_float2(v.x * scale, v.y * scale);
}

extern "C" void kernel_launch(void* const* d_in, const int* in_sizes, int n_in,
                              void* d_out, int out_size, void* d_ws, size_t ws_size,
                              hipStream_t stream) {
    const float* H    = (const float*)d_in[1];
    const int*   ei   = (const int*)d_in[2];
    const float* w1_1 = (const float*)d_in[3];
    const float* b1_1 = (const float*)d_in[4];
    const float* w1_2 = (const float*)d_in[5];
    const float* b1_2 = (const float*)d_in[6];
    const float* w2_1 = (const float*)d_in[7];
    const float* b2_1 = (const float*)d_in[8];
    const float* w2_2 = (const float*)d_in[9];
    const float* b2_2 = (const float*)d_in[10];

    int N = in_sizes[1] / D;
    int E = in_sizes[2] / 2;
    const int* src = ei;
    const int* dst = ei + E;

    float* out = (float*)d_out;

    // Workspace layout (floats). Hn lives in d_out (fully rewritten by k_finalize).
    float* ws  = (float*)d_ws;
    float* PQ  = ws;                          // 2*N*128  (P,Q; later reused for R,T)
    float* C   = PQ + (size_t)2 * N * D;      // N*128
    float* S   = C  + (size_t)N * D;          // N*128
    float* cnt = S  + (size_t)N * D;          // N
    float* P = PQ;
    float* Q = PQ + (size_t)N * D;
    float* Hn = out;                          // scratch until k_finalize

    // zero C, S, cnt (contiguous)
    hipMemsetAsync(C, 0, ((size_t)2 * N * D + N) * sizeof(float), stream);

    k_normalize<<<(N + 3) / 4, 256, 0, stream>>>(H, Hn, N);
    k_gemm128<<<(N + 63) / 64, 256, 0, stream>>>(Hn, w1_1, P, N);              // top half of w1_1
    k_gemm128<<<(N + 63) / 64, 256, 0, stream>>>(Hn, w1_1 + 128 * 128, Q, N);  // bottom half
    k_edge_mlp1<<<(E + 31) / 32, 256, 0, stream>>>(src, dst, P, Q, b1_1, w1_2, b1_2, C, E);
    k_gemm128<<<(N + 63) / 64, 256, 0, stream>>>(C, w2_1, P, N);               // R -> P buffer
    k_gemm128<<<(N + 63) / 64, 256, 0, stream>>>(C, w2_1 + 128 * 128, Q, N);   // T -> Q buffer
    k_edge_curv<<<(E + 3) / 4, 256, 0, stream>>>(src, dst, Hn, P, Q, b2_1, w2_2, b2_2, S, cnt, E);
    k_finalize<<<(N + 3) / 4, 256, 0, stream>>>(S, cnt, out, N);
}

// Round 2
// 950.974 us; speedup vs baseline: 6.7343x; 6.7343x over previous
//
#include <hip/hip_runtime.h>
#include <hip/hip_bf16.h>

#define D 128
#define EPS 1e-8f

// ---------------- K1: row-normalize H -> Hn ----------------
__global__ void k_normalize(const float* __restrict__ H, float* __restrict__ Hn, int N) {
    int row = blockIdx.x * 4 + (threadIdx.x >> 6);
    int lane = threadIdx.x & 63;
    if (row >= N) return;
    float2 v = reinterpret_cast<const float2*>(H + (size_t)row * D)[lane];
    float ss = v.x * v.x + v.y * v.y;
    #pragma unroll
    for (int off = 32; off; off >>= 1) ss += __shfl_xor(ss, off, 64);
    float scale = 1.0f / (sqrtf(ss) + EPS);
    reinterpret_cast<float2*>(Hn + (size_t)row * D)[lane] =
        make_float2(v.x * scale, v.y * scale);
}

// ---------------- CSR build ----------------
__global__ void k_hist(const int* __restrict__ src, int* __restrict__ deg, int E) {
    for (int e = blockIdx.x * blockDim.x + threadIdx.x; e < E; e += gridDim.x * blockDim.x)
        atomicAdd(&deg[src[e]], 1);
}

// one block, 1024 threads: inclusive scan of deg -> rowptr[1..N], rowptr[0]=0
__global__ void k_scan(const int* __restrict__ deg, int* __restrict__ rowptr, int N) {
    __shared__ int wsum[16];
    __shared__ int carry;
    int t = threadIdx.x, lane = t & 63, w = t >> 6;
    if (t == 0) carry = 0;
    __syncthreads();
    for (int base = 0; base < N; base += 1024) {
        int i = base + t;
        int v = (i < N) ? deg[i] : 0;
        #pragma unroll
        for (int off = 1; off < 64; off <<= 1) {
            int u = __shfl_up(v, off, 64);
            if (lane >= off) v += u;
        }
        if (lane == 63) wsum[w] = v;
        __syncthreads();
        if (w == 0 && lane < 16) {
            int s = wsum[lane];
            #pragma unroll
            for (int off = 1; off < 16; off <<= 1) {
                int u = __shfl_up(s, off, 64);
                if (lane >= off) s += u;
            }
            wsum[lane] = s;
        }
        __syncthreads();
        int add = (w > 0 ? wsum[w - 1] : 0) + carry;
        int incl = v + add;
        if (i < N) rowptr[i + 1] = incl;
        __syncthreads();
        if (t == 1023) carry = incl;
        __syncthreads();
    }
    if (t == 0) rowptr[0] = 0;
}

__global__ void k_scatter(const int* __restrict__ src, const int* __restrict__ dst,
                          const int* __restrict__ rowptr, int* __restrict__ fill,
                          int* __restrict__ srcS, int* __restrict__ dstS, int E) {
    for (int e = blockIdx.x * blockDim.x + threadIdx.x; e < E; e += gridDim.x * blockDim.x) {
        int s = src[e];
        int pos = atomicAdd(&fill[s], 1);
        int idx = rowptr[s] + pos;
        srcS[idx] = s;
        dstS[idx] = dst[e];
    }
}

// ---------------- fp32 GEMM [N x 128] @ [128 x 128] -> [N x 128] ----------------
__global__ void k_gemm128(const float* __restrict__ A, const float* __restrict__ B,
                          float* __restrict__ out, int N) {
    __shared__ float As[64][40];
    __shared__ float Bs[32][128];
    int r0 = blockIdx.x * 64;
    int t = threadIdx.x;
    int c4 = (t & 31) * 4;
    int r8 = (t >> 5) * 8;
    float acc[8][4] = {};
    for (int k0 = 0; k0 < 128; k0 += 32) {
        __syncthreads();
        #pragma unroll
        for (int q = 0; q < 2; ++q) {
            int idx = t * 2 + q;
            int rr = idx >> 3;
            int kk = (idx & 7) * 4;
            int grow = r0 + rr;
            float4 av = (grow < N)
                ? *reinterpret_cast<const float4*>(A + (size_t)grow * 128 + k0 + kk)
                : make_float4(0.f, 0.f, 0.f, 0.f);
            *reinterpret_cast<float4*>(&As[rr][kk]) = av;
        }
        #pragma unroll
        for (int q = 0; q < 4; ++q) {
            int idx = q * 256 + t;
            int kk = idx >> 5;
            int cc = (idx & 31) * 4;
            *reinterpret_cast<float4*>(&Bs[kk][cc]) =
                *reinterpret_cast<const float4*>(B + (size_t)(k0 + kk) * 128 + cc);
        }
        __syncthreads();
        #pragma unroll 8
        for (int k = 0; k < 32; ++k) {
            float4 bv = *reinterpret_cast<const float4*>(&Bs[k][c4]);
            #pragma unroll
            for (int i = 0; i < 8; ++i) {
                float a = As[r8 + i][k];
                acc[i][0] += a * bv.x;
                acc[i][1] += a * bv.y;
                acc[i][2] += a * bv.z;
                acc[i][3] += a * bv.w;
            }
        }
    }
    #pragma unroll
    for (int i = 0; i < 8; ++i) {
        int grow = r0 + r8 + i;
        if (grow < N)
            *reinterpret_cast<float4*>(out + (size_t)grow * 128 + c4) =
                make_float4(acc[i][0], acc[i][1], acc[i][2], acc[i][3]);
    }
}

// ---------------- K3 (hot): per-edge mlp1 layer2 on SORTED edges ----------------
// 32 sorted edges per block. Segmented block reduction; plain store for complete
// nodes, atomicAdd only at block-boundary-cut nodes.
__global__ void k_edge_mlp1(const int* __restrict__ srcS, const int* __restrict__ dstS,
                            const int* __restrict__ rowptr,
                            const float* __restrict__ P, const float* __restrict__ Q,
                            const float* __restrict__ b1_1, const float* __restrict__ W12,
                            const float* __restrict__ b1_2, float* __restrict__ C, int E) {
    __shared__ float e1[32][133];
    __shared__ float Ws[64][128];
    __shared__ int ssrc[32], sdst[32];
    int t = threadIdx.x;
    int e0 = blockIdx.x * 32;
    if (t < 32) {
        int ge = e0 + t;
        ssrc[t] = (ge < E) ? srcS[ge] : -1;
        sdst[t] = (ge < E) ? dstS[ge] : 0;
    }
    __syncthreads();
    // stage e1 = relu(P[src]+Q[dst]+b1_1)
    {
        int es = t >> 3;
        int d0 = (t & 7) * 16;
        int sc = max(ssrc[es], 0);
        const float4* Pp = reinterpret_cast<const float4*>(P + (size_t)sc * 128 + d0);
        const float4* Qp = reinterpret_cast<const float4*>(Q + (size_t)sdst[es] * 128 + d0);
        const float4* bp = reinterpret_cast<const float4*>(b1_1 + d0);
        #pragma unroll
        for (int q = 0; q < 4; ++q) {
            float4 pv = Pp[q], qv = Qp[q], bv = bp[q];
            int dd = d0 + q * 4;
            e1[es][dd + 0] = fmaxf(pv.x + qv.x + bv.x, 0.f);
            e1[es][dd + 1] = fmaxf(pv.y + qv.y + bv.y, 0.f);
            e1[es][dd + 2] = fmaxf(pv.z + qv.z + bv.z, 0.f);
            e1[es][dd + 3] = fmaxf(pv.w + qv.w + bv.w, 0.f);
        }
    }
    int ec = t & 31;
    int f0 = (t >> 5) * 16;
    float acc[16];
    {
        const float4* b4 = reinterpret_cast<const float4*>(b1_2 + f0);
        #pragma unroll
        for (int q = 0; q < 4; ++q) {
            float4 bv = b4[q];
            acc[q * 4 + 0] = bv.x; acc[q * 4 + 1] = bv.y;
            acc[q * 4 + 2] = bv.z; acc[q * 4 + 3] = bv.w;
        }
    }
    for (int k0 = 0; k0 < 128; k0 += 64) {
        __syncthreads();
        #pragma unroll
        for (int q = 0; q < 8; ++q) {
            int idx = q * 256 + t;
            int kk = idx >> 5;
            int cc = (idx & 31) * 4;
            *reinterpret_cast<float4*>(&Ws[kk][cc]) =
                *reinterpret_cast<const float4*>(W12 + (size_t)(k0 + kk) * 128 + cc);
        }
        __syncthreads();
        #pragma unroll 4
        for (int k = 0; k < 64; ++k) {
            float xv = e1[ec][k0 + k];
            const float4* wr = reinterpret_cast<const float4*>(&Ws[k][f0]);
            float4 w0 = wr[0], w1 = wr[1], w2 = wr[2], w3 = wr[3];
            acc[0]  += xv * w0.x; acc[1]  += xv * w0.y; acc[2]  += xv * w0.z; acc[3]  += xv * w0.w;
            acc[4]  += xv * w1.x; acc[5]  += xv * w1.y; acc[6]  += xv * w1.z; acc[7]  += xv * w1.w;
            acc[8]  += xv * w2.x; acc[9]  += xv * w2.y; acc[10] += xv * w2.z; acc[11] += xv * w2.w;
            acc[12] += xv * w3.x; acc[13] += xv * w3.y; acc[14] += xv * w3.z; acc[15] += xv * w3.w;
        }
    }
    // write y = relu(acc) back into e1 (done reading it), then segmented reduce
    __syncthreads();
    #pragma unroll
    for (int q = 0; q < 4; ++q) {
        float4 yv = make_float4(fmaxf(acc[q * 4 + 0], 0.f), fmaxf(acc[q * 4 + 1], 0.f),
                                fmaxf(acc[q * 4 + 2], 0.f), fmaxf(acc[q * 4 + 3], 0.f));
        *reinterpret_cast<float4*>(&e1[ec][f0 + q * 4]) = yv;
    }
    __syncthreads();
    if (t < 128) {
        int f = t;
        float a = 0.f;
        for (int e = 0; e < 32; ++e) {
            int s = ssrc[e];
            if (s < 0) break;
            a += e1[e][f];
            bool end = (e == 31) || (ssrc[e + 1] != s);
            if (end) {
                int rs = rowptr[s], re = rowptr[s + 1];
                if (rs >= e0 && re <= e0 + 32)
                    C[(size_t)s * 128 + f] = a;          // node fully inside block
                else
                    atomicAdd(&C[(size_t)s * 128 + f], a);
                a = 0.f;
            }
        }
    }
}

// ---------------- K5: curvature + damped message on SORTED edges ----------------
// 32 edges/block, 8 threads per edge (16 feats each), segmented reduce like mlp1.
__global__ void k_edge_curv(const int* __restrict__ srcS, const int* __restrict__ dstS,
                            const int* __restrict__ rowptr,
                            const float* __restrict__ Hn,
                            const float* __restrict__ R, const float* __restrict__ T,
                            const float* __restrict__ b2_1, const float* __restrict__ w2_2,
                            const float* __restrict__ b2_2,
                            float* __restrict__ S, int E) {
    __shared__ float yl[32][132];
    __shared__ int ssrc[32];
    int t = threadIdx.x;
    int e0 = blockIdx.x * 32;
    if (t < 32) {
        int ge = e0 + t;
        ssrc[t] = (ge < E) ? srcS[ge] : -1;
    }
    __syncthreads();
    int es = t >> 3;
    int f0 = (t & 7) * 16;
    {
        int ge = e0 + es;
        int s = ssrc[es];
        int sc = max(s, 0);
        int dj = (ge < E) ? dstS[ge] : 0;
        float hi[16], hj[16], pcos = 0.f, pcur = 0.f;
        const float4* Hi4 = reinterpret_cast<const float4*>(Hn + (size_t)sc * 128 + f0);
        const float4* Hj4 = reinterpret_cast<const float4*>(Hn + (size_t)dj * 128 + f0);
        const float4* R4  = reinterpret_cast<const float4*>(R  + (size_t)sc * 128 + f0);
        const float4* T4  = reinterpret_cast<const float4*>(T  + (size_t)dj * 128 + f0);
        const float4* b4  = reinterpret_cast<const float4*>(b2_1 + f0);
        const float4* w4  = reinterpret_cast<const float4*>(w2_2 + f0);
        #pragma unroll
        for (int q = 0; q < 4; ++q) {
            float4 a = Hi4[q], b = Hj4[q];
            hi[q * 4 + 0] = a.x; hi[q * 4 + 1] = a.y; hi[q * 4 + 2] = a.z; hi[q * 4 + 3] = a.w;
            hj[q * 4 + 0] = b.x; hj[q * 4 + 1] = b.y; hj[q * 4 + 2] = b.z; hj[q * 4 + 3] = b.w;
            pcos += a.x * b.x + a.y * b.y + a.z * b.z + a.w * b.w;
            float4 rv = R4[q], tv = T4[q], bv = b4[q], wv = w4[q];
            pcur += fmaxf(rv.x + tv.x + bv.x, 0.f) * wv.x;
            pcur += fmaxf(rv.y + tv.y + bv.y, 0.f) * wv.y;
            pcur += fmaxf(rv.z + tv.z + bv.z, 0.f) * wv.z;
            pcur += fmaxf(rv.w + tv.w + bv.w, 0.f) * wv.w;
        }
        #pragma unroll
        for (int off = 1; off < 8; off <<= 1) {
            pcos += __shfl_xor(pcos, off, 64);
            pcur += __shfl_xor(pcur, off, 64);
        }
        float cur = pcur + b2_2[0];
        #pragma unroll
        for (int q = 0; q < 4; ++q) {
            float4 hv;
            hv.x = cur * (hj[q * 4 + 0] - pcos * hi[q * 4 + 0]);
            hv.y = cur * (hj[q * 4 + 1] - pcos * hi[q * 4 + 1]);
            hv.z = cur * (hj[q * 4 + 2] - pcos * hi[q * 4 + 2]);
            hv.w = cur * (hj[q * 4 + 3] - pcos * hi[q * 4 + 3]);
            *reinterpret_cast<float4*>(&yl[es][f0 + q * 4]) = hv;
        }
    }
    __syncthreads();
    if (t < 128) {
        int f = t;
        float a = 0.f;
        for (int e = 0; e < 32; ++e) {
            int s = ssrc[e];
            if (s < 0) break;
            a += yl[e][f];
            bool end = (e == 31) || (ssrc[e + 1] != s);
            if (end) {
                int rs = rowptr[s], re = rowptr[s + 1];
                if (rs >= e0 && re <= e0 + 32)
                    S[(size_t)s * 128 + f] = a;
                else
                    atomicAdd(&S[(size_t)s * 128 + f], a);
                a = 0.f;
            }
        }
    }
}

// ---------------- K6: mean + row-normalize -> out ----------------
__global__ void k_finalize(const float* __restrict__ S, const int* __restrict__ rowptr,
                           float* __restrict__ out, int N) {
    int row = blockIdx.x * 4 + (threadIdx.x >> 6);
    int lane = threadIdx.x & 63;
    if (row >= N) return;
    int deg = rowptr[row + 1] - rowptr[row];
    float inv = 1.0f / fmaxf((float)deg, 1.0f);
    float2 v = reinterpret_cast<const float2*>(S + (size_t)row * 128)[lane];
    v.x *= inv; v.y *= inv;
    float ss = v.x * v.x + v.y * v.y;
    #pragma unroll
    for (int off = 32; off; off >>= 1) ss += __shfl_xor(ss, off, 64);
    float scale = 1.0f / (sqrtf(ss) + EPS);
    reinterpret_cast<float2*>(out + (size_t)row * 128)[lane] =
        make_float2(v.x * scale, v.y * scale);
}

extern "C" void kernel_launch(void* const* d_in, const int* in_sizes, int n_in,
                              void* d_out, int out_size, void* d_ws, size_t ws_size,
                              hipStream_t stream) {
    const float* H    = (const float*)d_in[1];
    const int*   ei   = (const int*)d_in[2];
    const float* w1_1 = (const float*)d_in[3];
    const float* b1_1 = (const float*)d_in[4];
    const float* w1_2 = (const float*)d_in[5];
    const float* b1_2 = (const float*)d_in[6];
    const float* w2_1 = (const float*)d_in[7];
    const float* b2_1 = (const float*)d_in[8];
    const float* w2_2 = (const float*)d_in[9];
    const float* b2_2 = (const float*)d_in[10];

    int N = in_sizes[1] / D;
    int E = in_sizes[2] / 2;
    const int* src = ei;
    const int* dst = ei + E;

    float* out = (float*)d_out;

    // Workspace layout
    float* ws   = (float*)d_ws;
    float* P    = ws;                             // N*128
    float* Q    = P + (size_t)N * D;              // N*128
    float* Cb   = Q + (size_t)N * D;              // N*128 (C, then reused as S)
    int* deg    = (int*)(Cb + (size_t)N * D);     // N
    int* rowptr = deg + N;                        // N+1
    int* fill   = rowptr + N + 1;                 // N
    int* srcS   = fill + N;                       // E
    int* dstS   = srcS + E;                       // E
    float* Hn   = out;                            // scratch until k_finalize

    // zero C + deg + rowptr + fill (contiguous)
    hipMemsetAsync(Cb, 0, ((size_t)N * D + 3 * (size_t)N + 1) * sizeof(int), stream);

    k_normalize<<<(N + 3) / 4, 256, 0, stream>>>(H, Hn, N);
    k_hist<<<1024, 256, 0, stream>>>(src, deg, E);
    k_scan<<<1, 1024, 0, stream>>>(deg, rowptr, N);
    k_scatter<<<1024, 256, 0, stream>>>(src, dst, rowptr, fill, srcS, dstS, E);

    k_gemm128<<<(N + 63) / 64, 256, 0, stream>>>(Hn, w1_1, P, N);
    k_gemm128<<<(N + 63) / 64, 256, 0, stream>>>(Hn, w1_1 + 128 * 128, Q, N);
    k_edge_mlp1<<<(E + 31) / 32, 256, 0, stream>>>(srcS, dstS, rowptr, P, Q, b1_1, w1_2, b1_2, Cb, E);
    k_gemm128<<<(N + 63) / 64, 256, 0, stream>>>(Cb, w2_1, P, N);              // R
    k_gemm128<<<(N + 63) / 64, 256, 0, stream>>>(Cb, w2_1 + 128 * 128, Q, N);  // T
    hipMemsetAsync(Cb, 0, (size_t)N * D * sizeof(float), stream);              // S = Cb
    k_edge_curv<<<(E + 31) / 32, 256, 0, stream>>>(srcS, dstS, rowptr, Hn, P, Q, b2_1, w2_2, b2_2, Cb, E);
    k_finalize<<<(N + 3) / 4, 256, 0, stream>>>(Cb, rowptr, out, N);
}

// Round 3
// 663.135 us; speedup vs baseline: 9.6574x; 1.4341x over previous
//
#include <hip/hip_runtime.h>
#include <hip/hip_bf16.h>

#define D 128
#define EPS 1e-8f

typedef __attribute__((ext_vector_type(8))) short short8;
typedef __attribute__((ext_vector_type(4))) float f32x4;

__device__ inline short f2bf(float x) {
    union { float f; unsigned u; } v; v.f = x;
    unsigned u = v.u + 0x7fffu + ((v.u >> 16) & 1u);   // RNE
    return (short)(u >> 16);
}

// ---------------- K1: row-normalize H -> Hn ----------------
__global__ void k_normalize(const float* __restrict__ H, float* __restrict__ Hn, int N) {
    int row = blockIdx.x * 4 + (threadIdx.x >> 6);
    int lane = threadIdx.x & 63;
    if (row >= N) return;
    float2 v = reinterpret_cast<const float2*>(H + (size_t)row * D)[lane];
    float ss = v.x * v.x + v.y * v.y;
    #pragma unroll
    for (int off = 32; off; off >>= 1) ss += __shfl_xor(ss, off, 64);
    float scale = 1.0f / (sqrtf(ss) + EPS);
    reinterpret_cast<float2*>(Hn + (size_t)row * D)[lane] =
        make_float2(v.x * scale, v.y * scale);
}

// ---------------- CSR build ----------------
__global__ void k_hist(const int* __restrict__ src, int* __restrict__ deg, int E) {
    for (int e = blockIdx.x * blockDim.x + threadIdx.x; e < E; e += gridDim.x * blockDim.x)
        atomicAdd(&deg[src[e]], 1);
}

__global__ void k_scan(const int* __restrict__ deg, int* __restrict__ rowptr, int N) {
    __shared__ int wsum[16];
    __shared__ int carry;
    int t = threadIdx.x, lane = t & 63, w = t >> 6;
    if (t == 0) carry = 0;
    __syncthreads();
    for (int base = 0; base < N; base += 1024) {
        int i = base + t;
        int v = (i < N) ? deg[i] : 0;
        #pragma unroll
        for (int off = 1; off < 64; off <<= 1) {
            int u = __shfl_up(v, off, 64);
            if (lane >= off) v += u;
        }
        if (lane == 63) wsum[w] = v;
        __syncthreads();
        if (w == 0 && lane < 16) {
            int s = wsum[lane];
            #pragma unroll
            for (int off = 1; off < 16; off <<= 1) {
                int u = __shfl_up(s, off, 64);
                if (lane >= off) s += u;
            }
            wsum[lane] = s;
        }
        __syncthreads();
        int add = (w > 0 ? wsum[w - 1] : 0) + carry;
        int incl = v + add;
        if (i < N) rowptr[i + 1] = incl;
        __syncthreads();
        if (t == 1023) carry = incl;
        __syncthreads();
    }
    if (t == 0) rowptr[0] = 0;
}

__global__ void k_scatter(const int* __restrict__ src, const int* __restrict__ dst,
                          const int* __restrict__ rowptr, int* __restrict__ fill,
                          int* __restrict__ srcS, int* __restrict__ dstS, int E) {
    for (int e = blockIdx.x * blockDim.x + threadIdx.x; e < E; e += gridDim.x * blockDim.x) {
        int s = src[e];
        int pos = atomicAdd(&fill[s], 1);
        int idx = rowptr[s] + pos;
        srcS[idx] = s;
        dstS[idx] = dst[e];
    }
}

// ---------------- prep: W1_2 fp32 [k][n] -> bf16 transposed Wt [n][k] ----------------
__global__ void k_prep_w(const float* __restrict__ W, short* __restrict__ Wt) {
    int idx = blockIdx.x * 256 + threadIdx.x;     // 64 blocks x 256 = 16384
    int k = idx >> 7, n = idx & 127;
    Wt[n * 128 + k] = f2bf(W[k * 128 + n]);
}

// ---------------- fp32 GEMM [N x 128] @ [128 x 128] -> [N x 128] ----------------
__global__ void k_gemm128(const float* __restrict__ A, const float* __restrict__ B,
                          float* __restrict__ out, int N) {
    __shared__ float As[64][40];
    __shared__ float Bs[32][128];
    int r0 = blockIdx.x * 64;
    int t = threadIdx.x;
    int c4 = (t & 31) * 4;
    int r8 = (t >> 5) * 8;
    float acc[8][4] = {};
    for (int k0 = 0; k0 < 128; k0 += 32) {
        __syncthreads();
        #pragma unroll
        for (int q = 0; q < 2; ++q) {
            int idx = t * 2 + q;
            int rr = idx >> 3;
            int kk = (idx & 7) * 4;
            int grow = r0 + rr;
            float4 av = (grow < N)
                ? *reinterpret_cast<const float4*>(A + (size_t)grow * 128 + k0 + kk)
                : make_float4(0.f, 0.f, 0.f, 0.f);
            *reinterpret_cast<float4*>(&As[rr][kk]) = av;
        }
        #pragma unroll
        for (int q = 0; q < 4; ++q) {
            int idx = q * 256 + t;
            int kk = idx >> 5;
            int cc = (idx & 31) * 4;
            *reinterpret_cast<float4*>(&Bs[kk][cc]) =
                *reinterpret_cast<const float4*>(B + (size_t)(k0 + kk) * 128 + cc);
        }
        __syncthreads();
        #pragma unroll 8
        for (int k = 0; k < 32; ++k) {
            float4 bv = *reinterpret_cast<const float4*>(&Bs[k][c4]);
            #pragma unroll
            for (int i = 0; i < 8; ++i) {
                float a = As[r8 + i][k];
                acc[i][0] += a * bv.x;
                acc[i][1] += a * bv.y;
                acc[i][2] += a * bv.z;
                acc[i][3] += a * bv.w;
            }
        }
    }
    #pragma unroll
    for (int i = 0; i < 8; ++i) {
        int grow = r0 + r8 + i;
        if (grow < N)
            *reinterpret_cast<float4*>(out + (size_t)grow * 128 + c4) =
                make_float4(acc[i][0], acc[i][1], acc[i][2], acc[i][3]);
    }
}

// ---------------- K3 (hot): per-edge mlp1 layer2, bf16 MFMA, sorted edges ----------------
// 64 edges/block, 256 threads (4 waves). e1 bf16 staged in LDS (stride 136);
// W1_2^T bf16 B-frags held in registers per wave (no LDS traffic for W);
// y f32 in LDS (stride 129); 32-edge-chunk segmented reduce into C.
#define E1S 136
#define YS  129
__global__ void k_edge_mlp1(const int* __restrict__ srcS, const int* __restrict__ dstS,
                            const int* __restrict__ rowptr,
                            const float* __restrict__ P, const float* __restrict__ Q,
                            const float* __restrict__ b1_1, const short* __restrict__ Wt,
                            const float* __restrict__ b1_2, float* __restrict__ C, int E) {
    __shared__ short e1s[64 * E1S];
    __shared__ float y[64 * YS];
    __shared__ int ssrc[64], sdst[64];
    int t = threadIdx.x;
    int e0 = blockIdx.x * 64;
    if (t < 64) {
        int ge = e0 + t;
        ssrc[t] = (ge < E) ? srcS[ge] : -1;
        sdst[t] = (ge < E) ? dstS[ge] : 0;
    }
    int l = t & 63;
    int w = t >> 6;
    int n0 = w * 32;                       // this wave's 32-col slice
    // preload B fragments from global (bf16 Wt [n][k]); reused for whole block
    short8 bfrag[2][4];
    #pragma unroll
    for (int nt = 0; nt < 2; ++nt) {
        int col = n0 + nt * 16 + (l & 15);
        #pragma unroll
        for (int kt = 0; kt < 4; ++kt) {
            int krow = kt * 32 + (l >> 4) * 8;
            bfrag[nt][kt] = *reinterpret_cast<const short8*>(Wt + col * 128 + krow);
        }
    }
    float bias0 = b1_2[n0 + (l & 15)];
    float bias1 = b1_2[n0 + 16 + (l & 15)];
    __syncthreads();
    // stage e1 = bf16(relu(P[src]+Q[dst]+b1_1)); thread: edge t>>2, 32 ks at (t&3)*32
    {
        int er = t >> 2;
        int kb = (t & 3) * 32;
        int sc = max(ssrc[er], 0);
        int dj = sdst[er];
        const float4* Pp = reinterpret_cast<const float4*>(P + (size_t)sc * 128 + kb);
        const float4* Qp = reinterpret_cast<const float4*>(Q + (size_t)dj * 128 + kb);
        const float4* bp = reinterpret_cast<const float4*>(b1_1 + kb);
        #pragma unroll
        for (int q2 = 0; q2 < 4; ++q2) {
            float4 p0 = Pp[q2 * 2], p1 = Pp[q2 * 2 + 1];
            float4 q0 = Qp[q2 * 2], q1 = Qp[q2 * 2 + 1];
            float4 b0 = bp[q2 * 2], b1 = bp[q2 * 2 + 1];
            short8 sv;
            sv[0] = f2bf(fmaxf(p0.x + q0.x + b0.x, 0.f));
            sv[1] = f2bf(fmaxf(p0.y + q0.y + b0.y, 0.f));
            sv[2] = f2bf(fmaxf(p0.z + q0.z + b0.z, 0.f));
            sv[3] = f2bf(fmaxf(p0.w + q0.w + b0.w, 0.f));
            sv[4] = f2bf(fmaxf(p1.x + q1.x + b1.x, 0.f));
            sv[5] = f2bf(fmaxf(p1.y + q1.y + b1.y, 0.f));
            sv[6] = f2bf(fmaxf(p1.z + q1.z + b1.z, 0.f));
            sv[7] = f2bf(fmaxf(p1.w + q1.w + b1.w, 0.f));
            *reinterpret_cast<short8*>(&e1s[er * E1S + kb + q2 * 8]) = sv;
        }
    }
    __syncthreads();
    // MFMA: 4 m-tiles x (2 n-tiles x 4 k-tiles)
    #pragma unroll
    for (int mt = 0; mt < 4; ++mt) {
        int arow = mt * 16 + (l & 15);
        f32x4 acc0 = {0.f, 0.f, 0.f, 0.f};
        f32x4 acc1 = {0.f, 0.f, 0.f, 0.f};
        #pragma unroll
        for (int kt = 0; kt < 4; ++kt) {
            short8 af = *reinterpret_cast<const short8*>(
                &e1s[arow * E1S + kt * 32 + (l >> 4) * 8]);
            acc0 = __builtin_amdgcn_mfma_f32_16x16x32_bf16(af, bfrag[0][kt], acc0, 0, 0, 0);
            acc1 = __builtin_amdgcn_mfma_f32_16x16x32_bf16(af, bfrag[1][kt], acc1, 0, 0, 0);
        }
        #pragma unroll
        for (int j = 0; j < 4; ++j) {
            int row = mt * 16 + (l >> 4) * 4 + j;
            y[row * YS + n0 + (l & 15)]      = fmaxf(acc0[j] + bias0, 0.f);
            y[row * YS + n0 + 16 + (l & 15)] = fmaxf(acc1[j] + bias1, 0.f);
        }
    }
    __syncthreads();
    // segmented reduce in 32-edge chunks: thread -> chunk t>>7, col t&127
    {
        int chunk = t >> 7;
        int f = t & 127;
        int cb = chunk * 32;
        int c0 = e0 + cb;
        float a = 0.f;
        for (int i = 0; i < 32; ++i) {
            int e = cb + i;
            int s = ssrc[e];
            if (s < 0) break;
            a += y[e * YS + f];
            bool end = (i == 31) || (ssrc[e + 1] != s);
            if (end) {
                int rs = rowptr[s], re = rowptr[s + 1];
                if (rs >= c0 && re <= c0 + 32)
                    C[(size_t)s * 128 + f] = a;
                else
                    atomicAdd(&C[(size_t)s * 128 + f], a);
                a = 0.f;
            }
        }
    }
}

// ---------------- K5: curvature + damped message on SORTED edges ----------------
__global__ void k_edge_curv(const int* __restrict__ srcS, const int* __restrict__ dstS,
                            const int* __restrict__ rowptr,
                            const float* __restrict__ Hn,
                            const float* __restrict__ R, const float* __restrict__ T,
                            const float* __restrict__ b2_1, const float* __restrict__ w2_2,
                            const float* __restrict__ b2_2,
                            float* __restrict__ S, int E) {
    __shared__ float yl[32][132];
    __shared__ int ssrc[32];
    int t = threadIdx.x;
    int e0 = blockIdx.x * 32;
    if (t < 32) {
        int ge = e0 + t;
        ssrc[t] = (ge < E) ? srcS[ge] : -1;
    }
    __syncthreads();
    int es = t >> 3;
    int f0 = (t & 7) * 16;
    {
        int ge = e0 + es;
        int s = ssrc[es];
        int sc = max(s, 0);
        int dj = (ge < E) ? dstS[ge] : 0;
        float hi[16], hj[16], pcos = 0.f, pcur = 0.f;
        const float4* Hi4 = reinterpret_cast<const float4*>(Hn + (size_t)sc * 128 + f0);
        const float4* Hj4 = reinterpret_cast<const float4*>(Hn + (size_t)dj * 128 + f0);
        const float4* R4  = reinterpret_cast<const float4*>(R  + (size_t)sc * 128 + f0);
        const float4* T4  = reinterpret_cast<const float4*>(T  + (size_t)dj * 128 + f0);
        const float4* b4  = reinterpret_cast<const float4*>(b2_1 + f0);
        const float4* w4  = reinterpret_cast<const float4*>(w2_2 + f0);
        #pragma unroll
        for (int q = 0; q < 4; ++q) {
            float4 a = Hi4[q], b = Hj4[q];
            hi[q * 4 + 0] = a.x; hi[q * 4 + 1] = a.y; hi[q * 4 + 2] = a.z; hi[q * 4 + 3] = a.w;
            hj[q * 4 + 0] = b.x; hj[q * 4 + 1] = b.y; hj[q * 4 + 2] = b.z; hj[q * 4 + 3] = b.w;
            pcos += a.x * b.x + a.y * b.y + a.z * b.z + a.w * b.w;
            float4 rv = R4[q], tv = T4[q], bv = b4[q], wv = w4[q];
            pcur += fmaxf(rv.x + tv.x + bv.x, 0.f) * wv.x;
            pcur += fmaxf(rv.y + tv.y + bv.y, 0.f) * wv.y;
            pcur += fmaxf(rv.z + tv.z + bv.z, 0.f) * wv.z;
            pcur += fmaxf(rv.w + tv.w + bv.w, 0.f) * wv.w;
        }
        #pragma unroll
        for (int off = 1; off < 8; off <<= 1) {
            pcos += __shfl_xor(pcos, off, 64);
            pcur += __shfl_xor(pcur, off, 64);
        }
        float cur = pcur + b2_2[0];
        #pragma unroll
        for (int q = 0; q < 4; ++q) {
            float4 hv;
            hv.x = cur * (hj[q * 4 + 0] - pcos * hi[q * 4 + 0]);
            hv.y = cur * (hj[q * 4 + 1] - pcos * hi[q * 4 + 1]);
            hv.z = cur * (hj[q * 4 + 2] - pcos * hi[q * 4 + 2]);
            hv.w = cur * (hj[q * 4 + 3] - pcos * hi[q * 4 + 3]);
            *reinterpret_cast<float4*>(&yl[es][f0 + q * 4]) = hv;
        }
    }
    __syncthreads();
    if (t < 128) {
        int f = t;
        float a = 0.f;
        for (int e = 0; e < 32; ++e) {
            int s = ssrc[e];
            if (s < 0) break;
            a += yl[e][f];
            bool end = (e == 31) || (ssrc[e + 1] != s);
            if (end) {
                int rs = rowptr[s], re = rowptr[s + 1];
                if (rs >= e0 && re <= e0 + 32)
                    S[(size_t)s * 128 + f] = a;
                else
                    atomicAdd(&S[(size_t)s * 128 + f], a);
                a = 0.f;
            }
        }
    }
}

// ---------------- K6: mean + row-normalize -> out ----------------
__global__ void k_finalize(const float* __restrict__ S, const int* __restrict__ rowptr,
                           float* __restrict__ out, int N) {
    int row = blockIdx.x * 4 + (threadIdx.x >> 6);
    int lane = threadIdx.x & 63;
    if (row >= N) return;
    int deg = rowptr[row + 1] - rowptr[row];
    float inv = 1.0f / fmaxf((float)deg, 1.0f);
    float2 v = reinterpret_cast<const float2*>(S + (size_t)row * 128)[lane];
    v.x *= inv; v.y *= inv;
    float ss = v.x * v.x + v.y * v.y;
    #pragma unroll
    for (int off = 32; off; off >>= 1) ss += __shfl_xor(ss, off, 64);
    float scale = 1.0f / (sqrtf(ss) + EPS);
    reinterpret_cast<float2*>(out + (size_t)row * 128)[lane] =
        make_float2(v.x * scale, v.y * scale);
}

extern "C" void kernel_launch(void* const* d_in, const int* in_sizes, int n_in,
                              void* d_out, int out_size, void* d_ws, size_t ws_size,
                              hipStream_t stream) {
    const float* H    = (const float*)d_in[1];
    const int*   ei   = (const int*)d_in[2];
    const float* w1_1 = (const float*)d_in[3];
    const float* b1_1 = (const float*)d_in[4];
    const float* w1_2 = (const float*)d_in[5];
    const float* b1_2 = (const float*)d_in[6];
    const float* w2_1 = (const float*)d_in[7];
    const float* b2_1 = (const float*)d_in[8];
    const float* w2_2 = (const float*)d_in[9];
    const float* b2_2 = (const float*)d_in[10];

    int N = in_sizes[1] / D;
    int E = in_sizes[2] / 2;
    const int* src = ei;
    const int* dst = ei + E;

    float* out = (float*)d_out;

    float* ws   = (float*)d_ws;
    float* P    = ws;                             // N*128
    float* Q    = P + (size_t)N * D;              // N*128
    float* Cb   = Q + (size_t)N * D;              // N*128 (C, then reused as S)
    int* deg    = (int*)(Cb + (size_t)N * D);     // N
    int* rowptr = deg + N;                        // N+1
    int* fill   = rowptr + N + 1;                 // N
    int* srcS   = fill + N;                       // E
    int* dstS   = srcS + E;                       // E
    short* Wt   = (short*)(dstS + E);             // 128*128 bf16
    float* Hn   = out;                            // scratch until k_finalize

    hipMemsetAsync(Cb, 0, ((size_t)N * D + 3 * (size_t)N + 1) * sizeof(int), stream);

    k_normalize<<<(N + 3) / 4, 256, 0, stream>>>(H, Hn, N);
    k_hist<<<1024, 256, 0, stream>>>(src, deg, E);
    k_scan<<<1, 1024, 0, stream>>>(deg, rowptr, N);
    k_scatter<<<1024, 256, 0, stream>>>(src, dst, rowptr, fill, srcS, dstS, E);
    k_prep_w<<<64, 256, 0, stream>>>(w1_2, Wt);

    k_gemm128<<<(N + 63) / 64, 256, 0, stream>>>(Hn, w1_1, P, N);
    k_gemm128<<<(N + 63) / 64, 256, 0, stream>>>(Hn, w1_1 + 128 * 128, Q, N);
    k_edge_mlp1<<<(E + 63) / 64, 256, 0, stream>>>(srcS, dstS, rowptr, P, Q, b1_1, Wt, b1_2, Cb, E);
    k_gemm128<<<(N + 63) / 64, 256, 0, stream>>>(Cb, w2_1, P, N);              // R
    k_gemm128<<<(N + 63) / 64, 256, 0, stream>>>(Cb, w2_1 + 128 * 128, Q, N);  // T
    hipMemsetAsync(Cb, 0, (size_t)N * D * sizeof(float), stream);              // S = Cb
    k_edge_curv<<<(E + 31) / 32, 256, 0, stream>>>(srcS, dstS, rowptr, Hn, P, Q, b2_1, w2_2, b2_2, Cb, E);
    k_finalize<<<(N + 3) / 4, 256, 0, stream>>>(Cb, rowptr, out, N);
}

// Round 4
// 447.503 us; speedup vs baseline: 14.3109x; 1.4819x over previous
//
#include <hip/hip_runtime.h>
#include <hip/hip_bf16.h>

#define D 128
#define EPS 1e-8f
#define E1S 136

typedef __attribute__((ext_vector_type(8))) short short8;
typedef __attribute__((ext_vector_type(4))) float f32x4;

__device__ inline short f2bf(float x) {
    union { float f; unsigned u; } v; v.f = x;
    unsigned u = v.u + 0x7fffu + ((v.u >> 16) & 1u);   // RNE
    return (short)(u >> 16);
}
__device__ inline float b2f(short s) {
    union { unsigned u; float f; } v;
    v.u = ((unsigned)(unsigned short)s) << 16;
    return v.f;
}

// ---------------- K1: row-normalize H -> Hn ----------------
__global__ void k_normalize(const float* __restrict__ H, float* __restrict__ Hn, int N) {
    int row = blockIdx.x * 4 + (threadIdx.x >> 6);
    int lane = threadIdx.x & 63;
    if (row >= N) return;
    float2 v = reinterpret_cast<const float2*>(H + (size_t)row * D)[lane];
    float ss = v.x * v.x + v.y * v.y;
    #pragma unroll
    for (int off = 32; off; off >>= 1) ss += __shfl_xor(ss, off, 64);
    float scale = 1.0f / (sqrtf(ss) + EPS);
    reinterpret_cast<float2*>(Hn + (size_t)row * D)[lane] =
        make_float2(v.x * scale, v.y * scale);
}

// ---------------- CSR build ----------------
__global__ void k_hist(const int* __restrict__ src, int* __restrict__ deg, int E) {
    for (int e = blockIdx.x * blockDim.x + threadIdx.x; e < E; e += gridDim.x * blockDim.x)
        atomicAdd(&deg[src[e]], 1);
}

// one block, 1024 threads, 4 elems/thread
__global__ void k_scan(const int* __restrict__ deg, int* __restrict__ rowptr, int N) {
    __shared__ int wsum[16];
    __shared__ int carry;
    int t = threadIdx.x, lane = t & 63, w = t >> 6;
    if (t == 0) carry = 0;
    __syncthreads();
    for (int base = 0; base < N; base += 4096) {
        int i0 = base + t * 4;
        int a = 0, b = 0, c = 0, d = 0;
        if (i0 + 3 < N) {
            int4 v4 = *reinterpret_cast<const int4*>(deg + i0);
            a = v4.x; b = v4.y; c = v4.z; d = v4.w;
        } else {
            if (i0 < N) a = deg[i0];
            if (i0 + 1 < N) b = deg[i0 + 1];
            if (i0 + 2 < N) c = deg[i0 + 2];
            if (i0 + 3 < N) d = deg[i0 + 3];
        }
        int s1 = a + b, s2 = s1 + c, s3 = s2 + d;
        int v = s3;
        #pragma unroll
        for (int off = 1; off < 64; off <<= 1) {
            int u = __shfl_up(v, off, 64);
            if (lane >= off) v += u;
        }
        if (lane == 63) wsum[w] = v;
        __syncthreads();
        if (w == 0 && lane < 16) {
            int s = wsum[lane];
            #pragma unroll
            for (int off = 1; off < 16; off <<= 1) {
                int u = __shfl_up(s, off, 64);
                if (lane >= off) s += u;
            }
            wsum[lane] = s;
        }
        __syncthreads();
        int add = (w > 0 ? wsum[w - 1] : 0) + carry;
        int incl = v + add;
        int pre = incl - s3;
        if (i0 < N)     rowptr[i0 + 1] = pre + a;
        if (i0 + 1 < N) rowptr[i0 + 2] = pre + s1;
        if (i0 + 2 < N) rowptr[i0 + 3] = pre + s2;
        if (i0 + 3 < N) rowptr[i0 + 4] = pre + s3;
        __syncthreads();
        if (t == 1023) carry = incl;
        __syncthreads();
    }
    if (t == 0) rowptr[0] = 0;
}

__global__ void k_scatter(const int* __restrict__ src, const int* __restrict__ dst,
                          const int* __restrict__ rowptr, int* __restrict__ fill,
                          int* __restrict__ srcS, int* __restrict__ dstS, int E) {
    for (int e = blockIdx.x * blockDim.x + threadIdx.x; e < E; e += gridDim.x * blockDim.x) {
        int s = src[e];
        int pos = atomicAdd(&fill[s], 1);
        int idx = rowptr[s] + pos;
        srcS[idx] = s;
        dstS[idx] = dst[e];
    }
}

// ---------------- prep: 5 weight matrices fp32 [k][n] -> bf16 transposed [n][k] ----------------
// m: 0=w1_1 top, 1=w1_1 bot, 2=w1_2, 3=w2_1 top, 4=w2_1 bot
__global__ void k_prep_all(const float* __restrict__ w1_1, const float* __restrict__ w1_2,
                           const float* __restrict__ w2_1, short* __restrict__ Wt) {
    int b = blockIdx.x;                       // 0..319
    int m = b >> 6;
    int idx = (b & 63) * 256 + threadIdx.x;   // 0..16383
    int k = idx >> 7, n = idx & 127;
    const float* W = (m == 0) ? w1_1
                   : (m == 1) ? w1_1 + 16384
                   : (m == 2) ? w1_2
                   : (m == 3) ? w2_1
                              : w2_1 + 16384;
    Wt[m * 16384 + n * 128 + k] = f2bf(W[k * 128 + n]);
}

// ---------------- MFMA GEMM: [N x 128] fp32 @ Wt bf16 -> bf16 [N x 128] ----------------
// 64 rows/block, 4 waves x 32-col slices; A staged bf16 in LDS; result repacked
// through LDS for coalesced short8 stores.
__global__ __launch_bounds__(256, 6)
void k_gemm_mfma(const float* __restrict__ A, const short* __restrict__ Wt,
                 short* __restrict__ out, int N) {
    __shared__ short As[64 * E1S];
    int t = threadIdx.x;
    int r0 = blockIdx.x * 64;
    int l = t & 63, w = t >> 6, n0 = w * 32;
    {
        int er = t >> 2, kb = (t & 3) * 32;
        int row = r0 + er;
        int rc = min(row, N - 1);
        const float4* Ap = reinterpret_cast<const float4*>(A + (size_t)rc * 128 + kb);
        #pragma unroll
        for (int q = 0; q < 4; ++q) {
            float4 a0 = Ap[q * 2], a1 = Ap[q * 2 + 1];
            short8 sv;
            sv[0] = f2bf(a0.x); sv[1] = f2bf(a0.y); sv[2] = f2bf(a0.z); sv[3] = f2bf(a0.w);
            sv[4] = f2bf(a1.x); sv[5] = f2bf(a1.y); sv[6] = f2bf(a1.z); sv[7] = f2bf(a1.w);
            *reinterpret_cast<short8*>(&As[er * E1S + kb + q * 8]) = sv;
        }
    }
    short8 bfrag[2][4];
    #pragma unroll
    for (int nt = 0; nt < 2; ++nt) {
        int col = n0 + nt * 16 + (l & 15);
        #pragma unroll
        for (int kt = 0; kt < 4; ++kt)
            bfrag[nt][kt] = *reinterpret_cast<const short8*>(Wt + col * 128 + kt * 32 + (l >> 4) * 8);
    }
    __syncthreads();
    f32x4 acc[4][2];
    #pragma unroll
    for (int mt = 0; mt < 4; ++mt) { acc[mt][0] = (f32x4){0,0,0,0}; acc[mt][1] = (f32x4){0,0,0,0}; }
    #pragma unroll
    for (int mt = 0; mt < 4; ++mt) {
        int arow = mt * 16 + (l & 15);
        #pragma unroll
        for (int kt = 0; kt < 4; ++kt) {
            short8 af = *reinterpret_cast<const short8*>(&As[arow * E1S + kt * 32 + (l >> 4) * 8]);
            acc[mt][0] = __builtin_amdgcn_mfma_f32_16x16x32_bf16(af, bfrag[0][kt], acc[mt][0], 0, 0, 0);
            acc[mt][1] = __builtin_amdgcn_mfma_f32_16x16x32_bf16(af, bfrag[1][kt], acc[mt][1], 0, 0, 0);
        }
    }
    __syncthreads();
    #pragma unroll
    for (int mt = 0; mt < 4; ++mt)
        #pragma unroll
        for (int j = 0; j < 4; ++j) {
            int row = mt * 16 + (l >> 4) * 4 + j;
            As[row * E1S + n0 + (l & 15)]      = f2bf(acc[mt][0][j]);
            As[row * E1S + n0 + 16 + (l & 15)] = f2bf(acc[mt][1][j]);
        }
    __syncthreads();
    {
        int er = t >> 2, kb = (t & 3) * 32;
        int row = r0 + er;
        if (row < N) {
            #pragma unroll
            for (int q = 0; q < 4; ++q)
                *reinterpret_cast<short8*>(out + (size_t)row * 128 + kb + q * 8) =
                    *reinterpret_cast<const short8*>(&As[er * E1S + kb + q * 8]);
        }
    }
}

// ---------------- K3 (hot): per-edge mlp1 layer2, bf16 MFMA, sorted edges ----------------
// 64 edges/block, 4 waves. e1 bf16 in LDS; y written back bf16 into same buffer
// (LDS ~18 KB -> high occupancy); 32-edge-chunk segmented reduce into C (fp32).
__global__ __launch_bounds__(256, 6)
void k_edge_mlp1(const int* __restrict__ srcS, const int* __restrict__ dstS,
                 const int* __restrict__ rowptr,
                 const short* __restrict__ P, const short* __restrict__ Q,
                 const float* __restrict__ b1_1, const short* __restrict__ Wt,
                 const float* __restrict__ b1_2, float* __restrict__ C, int E) {
    __shared__ short e1s[64 * E1S];
    __shared__ int ssrc[64], sdst[64];
    int t = threadIdx.x;
    int e0 = blockIdx.x * 64;
    if (t < 64) {
        int ge = e0 + t;
        ssrc[t] = (ge < E) ? srcS[ge] : -1;
        sdst[t] = (ge < E) ? dstS[ge] : 0;
    }
    int l = t & 63, w = t >> 6, n0 = w * 32;
    float bias0 = b1_2[n0 + (l & 15)];
    float bias1 = b1_2[n0 + 16 + (l & 15)];
    __syncthreads();
    // stage e1 = bf16(relu(P[src]+Q[dst]+b1_1))
    {
        int er = t >> 2, kb = (t & 3) * 32;
        int sc = max(ssrc[er], 0), dj = sdst[er];
        const short8* Pp = reinterpret_cast<const short8*>(P + (size_t)sc * 128 + kb);
        const short8* Qp = reinterpret_cast<const short8*>(Q + (size_t)dj * 128 + kb);
        const float4* bp = reinterpret_cast<const float4*>(b1_1 + kb);
        #pragma unroll
        for (int q = 0; q < 4; ++q) {
            short8 pv = Pp[q], qv = Qp[q];
            float4 bA = bp[q * 2], bB = bp[q * 2 + 1];
            short8 sv;
            sv[0] = f2bf(fmaxf(b2f(pv[0]) + b2f(qv[0]) + bA.x, 0.f));
            sv[1] = f2bf(fmaxf(b2f(pv[1]) + b2f(qv[1]) + bA.y, 0.f));
            sv[2] = f2bf(fmaxf(b2f(pv[2]) + b2f(qv[2]) + bA.z, 0.f));
            sv[3] = f2bf(fmaxf(b2f(pv[3]) + b2f(qv[3]) + bA.w, 0.f));
            sv[4] = f2bf(fmaxf(b2f(pv[4]) + b2f(qv[4]) + bB.x, 0.f));
            sv[5] = f2bf(fmaxf(b2f(pv[5]) + b2f(qv[5]) + bB.y, 0.f));
            sv[6] = f2bf(fmaxf(b2f(pv[6]) + b2f(qv[6]) + bB.z, 0.f));
            sv[7] = f2bf(fmaxf(b2f(pv[7]) + b2f(qv[7]) + bB.w, 0.f));
            *reinterpret_cast<short8*>(&e1s[er * E1S + kb + q * 8]) = sv;
        }
    }
    short8 bfrag[2][4];
    #pragma unroll
    for (int nt = 0; nt < 2; ++nt) {
        int col = n0 + nt * 16 + (l & 15);
        #pragma unroll
        for (int kt = 0; kt < 4; ++kt)
            bfrag[nt][kt] = *reinterpret_cast<const short8*>(Wt + col * 128 + kt * 32 + (l >> 4) * 8);
    }
    __syncthreads();
    f32x4 acc[4][2];
    #pragma unroll
    for (int mt = 0; mt < 4; ++mt) { acc[mt][0] = (f32x4){0,0,0,0}; acc[mt][1] = (f32x4){0,0,0,0}; }
    #pragma unroll
    for (int mt = 0; mt < 4; ++mt) {
        int arow = mt * 16 + (l & 15);
        #pragma unroll
        for (int kt = 0; kt < 4; ++kt) {
            short8 af = *reinterpret_cast<const short8*>(&e1s[arow * E1S + kt * 32 + (l >> 4) * 8]);
            acc[mt][0] = __builtin_amdgcn_mfma_f32_16x16x32_bf16(af, bfrag[0][kt], acc[mt][0], 0, 0, 0);
            acc[mt][1] = __builtin_amdgcn_mfma_f32_16x16x32_bf16(af, bfrag[1][kt], acc[mt][1], 0, 0, 0);
        }
    }
    __syncthreads();   // all e1s reads done
    // y = bf16(relu(acc + bias)) written back into e1s
    #pragma unroll
    for (int mt = 0; mt < 4; ++mt)
        #pragma unroll
        for (int j = 0; j < 4; ++j) {
            int row = mt * 16 + (l >> 4) * 4 + j;
            e1s[row * E1S + n0 + (l & 15)]      = f2bf(fmaxf(acc[mt][0][j] + bias0, 0.f));
            e1s[row * E1S + n0 + 16 + (l & 15)] = f2bf(fmaxf(acc[mt][1][j] + bias1, 0.f));
        }
    __syncthreads();
    // segmented reduce in 32-edge chunks
    {
        int chunk = t >> 7, f = t & 127;
        int cb = chunk * 32, c0 = e0 + cb;
        float a = 0.f;
        for (int i = 0; i < 32; ++i) {
            int e = cb + i;
            int s = ssrc[e];
            if (s < 0) break;
            a += b2f(e1s[e * E1S + f]);
            bool end = (i == 31) || (ssrc[e + 1] != s);
            if (end) {
                int rs = rowptr[s], re = rowptr[s + 1];
                if (rs >= c0 && re <= c0 + 32)
                    C[(size_t)s * 128 + f] = a;
                else
                    atomicAdd(&C[(size_t)s * 128 + f], a);
                a = 0.f;
            }
        }
    }
}

// ---------------- K5: curvature + damped message on SORTED edges ----------------
// R,T bf16; Hn/cos/message fp32.
__global__ void k_edge_curv(const int* __restrict__ srcS, const int* __restrict__ dstS,
                            const int* __restrict__ rowptr,
                            const float* __restrict__ Hn,
                            const short* __restrict__ R, const short* __restrict__ T,
                            const float* __restrict__ b2_1, const float* __restrict__ w2_2,
                            const float* __restrict__ b2_2,
                            float* __restrict__ S, int E) {
    __shared__ float yl[32][132];
    __shared__ int ssrc[32];
    int t = threadIdx.x;
    int e0 = blockIdx.x * 32;
    if (t < 32) {
        int ge = e0 + t;
        ssrc[t] = (ge < E) ? srcS[ge] : -1;
    }
    __syncthreads();
    int es = t >> 3;
    int f0 = (t & 7) * 16;
    {
        int ge = e0 + es;
        int s = ssrc[es];
        int sc = max(s, 0);
        int dj = (ge < E) ? dstS[ge] : 0;
        float hi[16], hj[16], rr[16], tt[16], pcos = 0.f, pcur = 0.f;
        const float4* Hi4 = reinterpret_cast<const float4*>(Hn + (size_t)sc * 128 + f0);
        const float4* Hj4 = reinterpret_cast<const float4*>(Hn + (size_t)dj * 128 + f0);
        const short8* R8  = reinterpret_cast<const short8*>(R + (size_t)sc * 128 + f0);
        const short8* T8  = reinterpret_cast<const short8*>(T + (size_t)dj * 128 + f0);
        #pragma unroll
        for (int q = 0; q < 2; ++q) {
            short8 rv = R8[q], tv = T8[q];
            #pragma unroll
            for (int j = 0; j < 8; ++j) { rr[q * 8 + j] = b2f(rv[j]); tt[q * 8 + j] = b2f(tv[j]); }
        }
        #pragma unroll
        for (int q = 0; q < 4; ++q) {
            float4 a = Hi4[q], b = Hj4[q];
            hi[q * 4 + 0] = a.x; hi[q * 4 + 1] = a.y; hi[q * 4 + 2] = a.z; hi[q * 4 + 3] = a.w;
            hj[q * 4 + 0] = b.x; hj[q * 4 + 1] = b.y; hj[q * 4 + 2] = b.z; hj[q * 4 + 3] = b.w;
            pcos += a.x * b.x + a.y * b.y + a.z * b.z + a.w * b.w;
            float4 bv = reinterpret_cast<const float4*>(b2_1 + f0)[q];
            float4 wv = reinterpret_cast<const float4*>(w2_2 + f0)[q];
            pcur += fmaxf(rr[q * 4 + 0] + tt[q * 4 + 0] + bv.x, 0.f) * wv.x;
            pcur += fmaxf(rr[q * 4 + 1] + tt[q * 4 + 1] + bv.y, 0.f) * wv.y;
            pcur += fmaxf(rr[q * 4 + 2] + tt[q * 4 + 2] + bv.z, 0.f) * wv.z;
            pcur += fmaxf(rr[q * 4 + 3] + tt[q * 4 + 3] + bv.w, 0.f) * wv.w;
        }
        #pragma unroll
        for (int off = 1; off < 8; off <<= 1) {
            pcos += __shfl_xor(pcos, off, 64);
            pcur += __shfl_xor(pcur, off, 64);
        }
        float cur = pcur + b2_2[0];
        #pragma unroll
        for (int q = 0; q < 4; ++q) {
            float4 hv;
            hv.x = cur * (hj[q * 4 + 0] - pcos * hi[q * 4 + 0]);
            hv.y = cur * (hj[q * 4 + 1] - pcos * hi[q * 4 + 1]);
            hv.z = cur * (hj[q * 4 + 2] - pcos * hi[q * 4 + 2]);
            hv.w = cur * (hj[q * 4 + 3] - pcos * hi[q * 4 + 3]);
            *reinterpret_cast<float4*>(&yl[es][f0 + q * 4]) = hv;
        }
    }
    __syncthreads();
    if (t < 128) {
        int f = t;
        float a = 0.f;
        for (int e = 0; e < 32; ++e) {
            int s = ssrc[e];
            if (s < 0) break;
            a += yl[e][f];
            bool end = (e == 31) || (ssrc[e + 1] != s);
            if (end) {
                int rs = rowptr[s], re = rowptr[s + 1];
                if (rs >= e0 && re <= e0 + 32)
                    S[(size_t)s * 128 + f] = a;
                else
                    atomicAdd(&S[(size_t)s * 128 + f], a);
                a = 0.f;
            }
        }
    }
}

// ---------------- K6: mean + row-normalize -> out ----------------
__global__ void k_finalize(const float* __restrict__ S, const int* __restrict__ rowptr,
                           float* __restrict__ out, int N) {
    int row = blockIdx.x * 4 + (threadIdx.x >> 6);
    int lane = threadIdx.x & 63;
    if (row >= N) return;
    int deg = rowptr[row + 1] - rowptr[row];
    float inv = 1.0f / fmaxf((float)deg, 1.0f);
    float2 v = reinterpret_cast<const float2*>(S + (size_t)row * 128)[lane];
    v.x *= inv; v.y *= inv;
    float ss = v.x * v.x + v.y * v.y;
    #pragma unroll
    for (int off = 32; off; off >>= 1) ss += __shfl_xor(ss, off, 64);
    float scale = 1.0f / (sqrtf(ss) + EPS);
    reinterpret_cast<float2*>(out + (size_t)row * 128)[lane] =
        make_float2(v.x * scale, v.y * scale);
}

extern "C" void kernel_launch(void* const* d_in, const int* in_sizes, int n_in,
                              void* d_out, int out_size, void* d_ws, size_t ws_size,
                              hipStream_t stream) {
    const float* H    = (const float*)d_in[1];
    const int*   ei   = (const int*)d_in[2];
    const float* w1_1 = (const float*)d_in[3];
    const float* b1_1 = (const float*)d_in[4];
    const float* w1_2 = (const float*)d_in[5];
    const float* b1_2 = (const float*)d_in[6];
    const float* w2_1 = (const float*)d_in[7];
    const float* b2_1 = (const float*)d_in[8];
    const float* w2_2 = (const float*)d_in[9];
    const float* b2_2 = (const float*)d_in[10];

    int N = in_sizes[1] / D;
    int E = in_sizes[2] / 2;
    const int* src = ei;
    const int* dst = ei + E;

    float* out = (float*)d_out;

    // Workspace layout (16B-aligned segments)
    short* Pb   = (short*)d_ws;                   // N*128 bf16
    short* Qb   = Pb + (size_t)N * D;             // N*128 bf16
    float* Cb   = (float*)(Qb + (size_t)N * D);   // N*128 fp32 (C, then reused as S)
    short* Wt   = (short*)(Cb + (size_t)N * D);   // 5 * 128*128 bf16
    int* deg    = (int*)(Wt + 5 * 16384);         // N
    int* rowptr = deg + N;                        // N+1
    int* fill   = rowptr + N + 1;                 // N
    int* srcS   = fill + N;                       // E
    int* dstS   = srcS + E;                       // E
    float* Hn   = out;                            // scratch until k_finalize

    // zero Cb + Wt + deg + rowptr + fill (contiguous; Wt rewritten by prep)
    size_t zbytes = (size_t)N * D * 4 + 5 * 16384 * 2 + (3 * (size_t)N + 1) * 4;
    hipMemsetAsync(Cb, 0, zbytes, stream);

    k_normalize<<<(N + 3) / 4, 256, 0, stream>>>(H, Hn, N);
    k_hist<<<1024, 256, 0, stream>>>(src, deg, E);
    k_scan<<<1, 1024, 0, stream>>>(deg, rowptr, N);
    k_scatter<<<1024, 256, 0, stream>>>(src, dst, rowptr, fill, srcS, dstS, E);
    k_prep_all<<<320, 256, 0, stream>>>(w1_1, w1_2, w2_1, Wt);

    k_gemm_mfma<<<(N + 63) / 64, 256, 0, stream>>>(Hn, Wt + 0 * 16384, Pb, N);
    k_gemm_mfma<<<(N + 63) / 64, 256, 0, stream>>>(Hn, Wt + 1 * 16384, Qb, N);
    k_edge_mlp1<<<(E + 63) / 64, 256, 0, stream>>>(srcS, dstS, rowptr, Pb, Qb, b1_1,
                                                   Wt + 2 * 16384, b1_2, Cb, E);
    k_gemm_mfma<<<(N + 63) / 64, 256, 0, stream>>>(Cb, Wt + 3 * 16384, Pb, N);   // R
    k_gemm_mfma<<<(N + 63) / 64, 256, 0, stream>>>(Cb, Wt + 4 * 16384, Qb, N);   // T
    hipMemsetAsync(Cb, 0, (size_t)N * D * sizeof(float), stream);                // S = Cb
    k_edge_curv<<<(E + 31) / 32, 256, 0, stream>>>(srcS, dstS, rowptr, Hn, Pb, Qb,
                                                   b2_1, w2_2, b2_2, Cb, E);
    k_finalize<<<(N + 3) / 4, 256, 0, stream>>>(Cb, rowptr, out, N);
}

// Round 5
// 412.034 us; speedup vs baseline: 15.5428x; 1.0861x over previous
//
#include <hip/hip_runtime.h>
#include <hip/hip_bf16.h>

#define D 128
#define EPS 1e-8f
#define E1S 136

typedef __attribute__((ext_vector_type(8))) short short8;
typedef __attribute__((ext_vector_type(4))) float f32x4;
typedef unsigned int uint;

__device__ inline short f2bf(float x) {
    union { float f; unsigned u; } v; v.f = x;
    unsigned u = v.u + 0x7fffu + ((v.u >> 16) & 1u);   // RNE
    return (short)(u >> 16);
}
__device__ inline float b2f(short s) {
    union { unsigned u; float f; } v;
    v.u = ((unsigned)(unsigned short)s) << 16;
    return v.f;
}
__device__ inline float uasf(uint u) {
    union { unsigned u; float f; } v; v.u = u; return v.f;
}

// ---------------- K1: row-normalize H -> Hn (bf16 packed) ----------------
__global__ void k_normalize(const float* __restrict__ H, short* __restrict__ Hnb, int N) {
    int row = blockIdx.x * 4 + (threadIdx.x >> 6);
    int lane = threadIdx.x & 63;
    if (row >= N) return;
    float2 v = reinterpret_cast<const float2*>(H + (size_t)row * D)[lane];
    float ss = v.x * v.x + v.y * v.y;
    #pragma unroll
    for (int off = 32; off; off >>= 1) ss += __shfl_xor(ss, off, 64);
    float scale = 1.0f / (sqrtf(ss) + EPS);
    uint p = ((uint)(unsigned short)f2bf(v.x * scale)) |
             (((uint)(unsigned short)f2bf(v.y * scale)) << 16);
    reinterpret_cast<uint*>(Hnb + (size_t)row * D)[lane] = p;
}

// ---------------- CSR build ----------------
__global__ void k_hist(const int* __restrict__ src, int* __restrict__ deg, int E) {
    for (int e = blockIdx.x * blockDim.x + threadIdx.x; e < E; e += gridDim.x * blockDim.x)
        atomicAdd(&deg[src[e]], 1);
}

__global__ void k_scan(const int* __restrict__ deg, int* __restrict__ rowptr, int N) {
    __shared__ int wsum[16];
    __shared__ int carry;
    int t = threadIdx.x, lane = t & 63, w = t >> 6;
    if (t == 0) carry = 0;
    __syncthreads();
    for (int base = 0; base < N; base += 4096) {
        int i0 = base + t * 4;
        int a = 0, b = 0, c = 0, d = 0;
        if (i0 + 3 < N) {
            int4 v4 = *reinterpret_cast<const int4*>(deg + i0);
            a = v4.x; b = v4.y; c = v4.z; d = v4.w;
        } else {
            if (i0 < N) a = deg[i0];
            if (i0 + 1 < N) b = deg[i0 + 1];
            if (i0 + 2 < N) c = deg[i0 + 2];
            if (i0 + 3 < N) d = deg[i0 + 3];
        }
        int s1 = a + b, s2 = s1 + c, s3 = s2 + d;
        int v = s3;
        #pragma unroll
        for (int off = 1; off < 64; off <<= 1) {
            int u = __shfl_up(v, off, 64);
            if (lane >= off) v += u;
        }
        if (lane == 63) wsum[w] = v;
        __syncthreads();
        if (w == 0 && lane < 16) {
            int s = wsum[lane];
            #pragma unroll
            for (int off = 1; off < 16; off <<= 1) {
                int u = __shfl_up(s, off, 64);
                if (lane >= off) s += u;
            }
            wsum[lane] = s;
        }
        __syncthreads();
        int add = (w > 0 ? wsum[w - 1] : 0) + carry;
        int incl = v + add;
        int pre = incl - s3;
        if (i0 < N)     rowptr[i0 + 1] = pre + a;
        if (i0 + 1 < N) rowptr[i0 + 2] = pre + s1;
        if (i0 + 2 < N) rowptr[i0 + 3] = pre + s2;
        if (i0 + 3 < N) rowptr[i0 + 4] = pre + s3;
        __syncthreads();
        if (t == 1023) carry = incl;
        __syncthreads();
    }
    if (t == 0) rowptr[0] = 0;
}

__global__ void k_scatter(const int* __restrict__ src, const int* __restrict__ dst,
                          const int* __restrict__ rowptr, int* __restrict__ fill,
                          int* __restrict__ srcS, int* __restrict__ dstS, int E) {
    for (int e = blockIdx.x * blockDim.x + threadIdx.x; e < E; e += gridDim.x * blockDim.x) {
        int s = src[e];
        int pos = atomicAdd(&fill[s], 1);
        int idx = rowptr[s] + pos;
        srcS[idx] = s;
        dstS[idx] = dst[e];
    }
}

// ---------------- prep: 5 weight matrices fp32 [k][n] -> bf16 transposed [n][k] ----------------
__global__ void k_prep_all(const float* __restrict__ w1_1, const float* __restrict__ w1_2,
                           const float* __restrict__ w2_1, short* __restrict__ Wt) {
    int b = blockIdx.x;
    int m = b >> 6;
    int idx = (b & 63) * 256 + threadIdx.x;
    int k = idx >> 7, n = idx & 127;
    const float* W = (m == 0) ? w1_1
                   : (m == 1) ? w1_1 + 16384
                   : (m == 2) ? w1_2
                   : (m == 3) ? w2_1
                              : w2_1 + 16384;
    Wt[m * 16384 + n * 128 + k] = f2bf(W[k * 128 + n]);
}

// ---------------- dual MFMA GEMM: A[Nx128] @ {Wt0,Wt1} -> bf16 out0(+bias0), out1 ----------------
template <bool A_BF16>
__global__ __launch_bounds__(256, 4)
void k_gemm_dual(const void* __restrict__ Aptr, const short* __restrict__ Wt0,
                 const short* __restrict__ Wt1, const float* __restrict__ bias0,
                 short* __restrict__ out0, short* __restrict__ out1, int N) {
    __shared__ short As[64 * E1S];
    int t = threadIdx.x;
    int r0 = blockIdx.x * 64;
    int l = t & 63, w = t >> 6, n0 = w * 32;
    {
        int er = t >> 2, kb = (t & 3) * 32;
        int rc = min(r0 + er, N - 1);
        if (A_BF16) {
            const short8* Ap = reinterpret_cast<const short8*>((const short*)Aptr + (size_t)rc * 128 + kb);
            #pragma unroll
            for (int q = 0; q < 4; ++q)
                *reinterpret_cast<short8*>(&As[er * E1S + kb + q * 8]) = Ap[q];
        } else {
            const float4* Ap = reinterpret_cast<const float4*>((const float*)Aptr + (size_t)rc * 128 + kb);
            #pragma unroll
            for (int q = 0; q < 4; ++q) {
                float4 a0 = Ap[q * 2], a1 = Ap[q * 2 + 1];
                short8 sv;
                sv[0] = f2bf(a0.x); sv[1] = f2bf(a0.y); sv[2] = f2bf(a0.z); sv[3] = f2bf(a0.w);
                sv[4] = f2bf(a1.x); sv[5] = f2bf(a1.y); sv[6] = f2bf(a1.z); sv[7] = f2bf(a1.w);
                *reinterpret_cast<short8*>(&As[er * E1S + kb + q * 8]) = sv;
            }
        }
    }
    short8 bfrag[2][4];
    #pragma unroll
    for (int nt = 0; nt < 2; ++nt) {
        int col = n0 + nt * 16 + (l & 15);
        #pragma unroll
        for (int kt = 0; kt < 4; ++kt)
            bfrag[nt][kt] = *reinterpret_cast<const short8*>(Wt0 + col * 128 + kt * 32 + (l >> 4) * 8);
    }
    float b0a = bias0[n0 + (l & 15)];
    float b0b = bias0[n0 + 16 + (l & 15)];
    __syncthreads();
    f32x4 acc0[4][2], acc1[4][2];
    #pragma unroll
    for (int mt = 0; mt < 4; ++mt) {
        acc0[mt][0] = (f32x4){0,0,0,0}; acc0[mt][1] = (f32x4){0,0,0,0};
        acc1[mt][0] = (f32x4){0,0,0,0}; acc1[mt][1] = (f32x4){0,0,0,0};
    }
    #pragma unroll
    for (int mt = 0; mt < 4; ++mt) {
        int arow = mt * 16 + (l & 15);
        #pragma unroll
        for (int kt = 0; kt < 4; ++kt) {
            short8 af = *reinterpret_cast<const short8*>(&As[arow * E1S + kt * 32 + (l >> 4) * 8]);
            acc0[mt][0] = __builtin_amdgcn_mfma_f32_16x16x32_bf16(af, bfrag[0][kt], acc0[mt][0], 0, 0, 0);
            acc0[mt][1] = __builtin_amdgcn_mfma_f32_16x16x32_bf16(af, bfrag[1][kt], acc0[mt][1], 0, 0, 0);
        }
    }
    #pragma unroll
    for (int nt = 0; nt < 2; ++nt) {
        int col = n0 + nt * 16 + (l & 15);
        #pragma unroll
        for (int kt = 0; kt < 4; ++kt)
            bfrag[nt][kt] = *reinterpret_cast<const short8*>(Wt1 + col * 128 + kt * 32 + (l >> 4) * 8);
    }
    #pragma unroll
    for (int mt = 0; mt < 4; ++mt) {
        int arow = mt * 16 + (l & 15);
        #pragma unroll
        for (int kt = 0; kt < 4; ++kt) {
            short8 af = *reinterpret_cast<const short8*>(&As[arow * E1S + kt * 32 + (l >> 4) * 8]);
            acc1[mt][0] = __builtin_amdgcn_mfma_f32_16x16x32_bf16(af, bfrag[0][kt], acc1[mt][0], 0, 0, 0);
            acc1[mt][1] = __builtin_amdgcn_mfma_f32_16x16x32_bf16(af, bfrag[1][kt], acc1[mt][1], 0, 0, 0);
        }
    }
    __syncthreads();
    #pragma unroll
    for (int mt = 0; mt < 4; ++mt)
        #pragma unroll
        for (int j = 0; j < 4; ++j) {
            int row = mt * 16 + (l >> 4) * 4 + j;
            As[row * E1S + n0 + (l & 15)]      = f2bf(acc0[mt][0][j] + b0a);
            As[row * E1S + n0 + 16 + (l & 15)] = f2bf(acc0[mt][1][j] + b0b);
        }
    __syncthreads();
    {
        int er = t >> 2, kb = (t & 3) * 32;
        int row = r0 + er;
        if (row < N)
            #pragma unroll
            for (int q = 0; q < 4; ++q)
                *reinterpret_cast<short8*>(out0 + (size_t)row * 128 + kb + q * 8) =
                    *reinterpret_cast<const short8*>(&As[er * E1S + kb + q * 8]);
    }
    __syncthreads();
    #pragma unroll
    for (int mt = 0; mt < 4; ++mt)
        #pragma unroll
        for (int j = 0; j < 4; ++j) {
            int row = mt * 16 + (l >> 4) * 4 + j;
            As[row * E1S + n0 + (l & 15)]      = f2bf(acc1[mt][0][j]);
            As[row * E1S + n0 + 16 + (l & 15)] = f2bf(acc1[mt][1][j]);
        }
    __syncthreads();
    {
        int er = t >> 2, kb = (t & 3) * 32;
        int row = r0 + er;
        if (row < N)
            #pragma unroll
            for (int q = 0; q < 4; ++q)
                *reinterpret_cast<short8*>(out1 + (size_t)row * 128 + kb + q * 8) =
                    *reinterpret_cast<const short8*>(&As[er * E1S + kb + q * 8]);
    }
}

// ---------------- K3 (hot): per-edge mlp1 layer2, MFMA + in-register segmented reduce ----------------
__global__ __launch_bounds__(256, 5)
void k_edge_mlp1(const int* __restrict__ srcS, const int* __restrict__ dstS,
                 const int* __restrict__ rowptr,
                 const short* __restrict__ P, const short* __restrict__ Q,
                 const short* __restrict__ Wt, const float* __restrict__ b1_2,
                 float* __restrict__ C, int E) {
    __shared__ short e1s[64 * E1S];
    int t = threadIdx.x;
    int e0 = blockIdx.x * 64;
    int l = t & 63, w = t >> 6, n0 = w * 32;
    // stage e1 = bf16(relu(P'[src] + Q[dst]))   (b1_1 folded into P')
    {
        int er = t >> 2, kb = (t & 3) * 32;
        int ge = min(e0 + er, E - 1);
        int sc = srcS[ge], dj = dstS[ge];
        const short8* Pp = reinterpret_cast<const short8*>(P + (size_t)sc * 128 + kb);
        const short8* Qp = reinterpret_cast<const short8*>(Q + (size_t)dj * 128 + kb);
        #pragma unroll
        for (int q = 0; q < 4; ++q) {
            short8 pv = Pp[q], qv = Qp[q];
            short8 sv;
            #pragma unroll
            for (int i = 0; i < 8; ++i)
                sv[i] = f2bf(fmaxf(b2f(pv[i]) + b2f(qv[i]), 0.f));
            *reinterpret_cast<short8*>(&e1s[er * E1S + kb + q * 8]) = sv;
        }
    }
    short8 bfrag[2][4];
    #pragma unroll
    for (int nt = 0; nt < 2; ++nt) {
        int col = n0 + nt * 16 + (l & 15);
        #pragma unroll
        for (int kt = 0; kt < 4; ++kt)
            bfrag[nt][kt] = *reinterpret_cast<const short8*>(Wt + col * 128 + kt * 32 + (l >> 4) * 8);
    }
    float bias0 = b1_2[n0 + (l & 15)];
    float bias1 = b1_2[n0 + 16 + (l & 15)];
    __syncthreads();
    f32x4 acc[4][2];
    #pragma unroll
    for (int mt = 0; mt < 4; ++mt) { acc[mt][0] = (f32x4){0,0,0,0}; acc[mt][1] = (f32x4){0,0,0,0}; }
    #pragma unroll
    for (int mt = 0; mt < 4; ++mt) {
        int arow = mt * 16 + (l & 15);
        #pragma unroll
        for (int kt = 0; kt < 4; ++kt) {
            short8 af = *reinterpret_cast<const short8*>(&e1s[arow * E1S + kt * 32 + (l >> 4) * 8]);
            acc[mt][0] = __builtin_amdgcn_mfma_f32_16x16x32_bf16(af, bfrag[0][kt], acc[mt][0], 0, 0, 0);
            acc[mt][1] = __builtin_amdgcn_mfma_f32_16x16x32_bf16(af, bfrag[1][kt], acc[mt][1], 0, 0, 0);
        }
    }
    // y = relu(acc + bias) in-register
    #pragma unroll
    for (int mt = 0; mt < 4; ++mt)
        #pragma unroll
        for (int j = 0; j < 4; ++j) {
            acc[mt][0][j] = fmaxf(acc[mt][0][j] + bias0, 0.f);
            acc[mt][1][j] = fmaxf(acc[mt][1][j] + bias1, 0.f);
        }
    // in-register segmented reduce over MFMA rows (= edges)
    int myv = (e0 + l < E) ? srcS[e0 + l] : -1;
    int pv = __shfl_up(myv, 1, 64);
    bool head = (l == 0) || (myv != pv);
    unsigned long long validm = __ballot(myv >= 0);
    unsigned long long hm = __ballot(head) & validm;
    int nvalid = __popcll(validm);
    int grp = l >> 4;
    while (hm) {
        int lo = __builtin_ctzll(hm);
        hm &= hm - 1;
        int hi = hm ? __builtin_ctzll(hm) : nvalid;
        int s = __shfl(myv, lo, 64);
        float v0 = 0.f, v1 = 0.f;
        #pragma unroll
        for (int mt = 0; mt < 4; ++mt)
            #pragma unroll
            for (int j = 0; j < 4; ++j) {
                int row = mt * 16 + grp * 4 + j;
                bool in = (row >= lo) && (row < hi);
                v0 += in ? acc[mt][0][j] : 0.f;
                v1 += in ? acc[mt][1][j] : 0.f;
            }
        v0 += __shfl_xor(v0, 16, 64); v0 += __shfl_xor(v0, 32, 64);
        v1 += __shfl_xor(v1, 16, 64); v1 += __shfl_xor(v1, 32, 64);
        if (l < 16) {
            int rs = rowptr[s], re = rowptr[s + 1];
            float* cp = C + (size_t)s * 128 + n0 + l;
            if (rs >= e0 && re <= e0 + 64) {
                cp[0] = v0; cp[16] = v1;
            } else {
                atomicAdd(cp, v0); atomicAdd(cp + 16, v1);
            }
        }
    }
}

// ---------------- K5a: per-edge scalars (cur, cos) ----------------
// 16 lanes/edge, 4 edges/wave, 16 edges/block
__global__ void k_edge_scal(const int* __restrict__ srcS, const int* __restrict__ dstS,
                            const short* __restrict__ Hnb,
                            const short* __restrict__ Rb, const short* __restrict__ Tb,
                            const float* __restrict__ w2_2, const float* __restrict__ b2_2,
                            float2* __restrict__ CC, int E) {
    int t = threadIdx.x;
    int e = blockIdx.x * 16 + (t >> 4);
    int sl = t & 15;
    if (e >= E) return;
    int s = srcS[e], d = dstS[e];
    uint4 hiu = reinterpret_cast<const uint4*>(Hnb + (size_t)s * 128)[sl];
    uint4 hju = reinterpret_cast<const uint4*>(Hnb + (size_t)d * 128)[sl];
    uint4 rvu = reinterpret_cast<const uint4*>(Rb + (size_t)s * 128)[sl];
    uint4 tvu = reinterpret_cast<const uint4*>(Tb + (size_t)d * 128)[sl];
    float4 wv0 = reinterpret_cast<const float4*>(w2_2)[sl * 2];
    float4 wv1 = reinterpret_cast<const float4*>(w2_2)[sl * 2 + 1];
    const float* wvp = &wv0.x;
    float pcos = 0.f, pcur = 0.f;
    const uint* hip = &hiu.x;
    const uint* hjp = &hju.x;
    const uint* rvp = &rvu.x;
    const uint* tvp = &tvu.x;
    #pragma unroll
    for (int k = 0; k < 4; ++k) {
        float hix = uasf(hip[k] << 16), hiy = uasf(hip[k] & 0xffff0000u);
        float hjx = uasf(hjp[k] << 16), hjy = uasf(hjp[k] & 0xffff0000u);
        float rvx = uasf(rvp[k] << 16), rvy = uasf(rvp[k] & 0xffff0000u);
        float tvx = uasf(tvp[k] << 16), tvy = uasf(tvp[k] & 0xffff0000u);
        float w0 = (k < 2) ? ((k == 0) ? wv0.x : wv0.z) : ((k == 2) ? wv1.x : wv1.z);
        float w1 = (k < 2) ? ((k == 0) ? wv0.y : wv0.w) : ((k == 2) ? wv1.y : wv1.w);
        pcos += hix * hjx + hiy * hjy;
        pcur += fmaxf(rvx + tvx, 0.f) * w0 + fmaxf(rvy + tvy, 0.f) * w1;
    }
    (void)wvp;
    #pragma unroll
    for (int off = 1; off < 16; off <<= 1) {
        pcos += __shfl_xor(pcos, off, 64);
        pcur += __shfl_xor(pcur, off, 64);
    }
    if (sl == 0)
        CC[e] = make_float2(pcur + b2_2[0], pcos);
}

// ---------------- K5b: node-centric message sum + mean + normalize -> out ----------------
__global__ void k_node_curv(const int* __restrict__ dstS, const int* __restrict__ rowptr,
                            const short* __restrict__ Hnb, const float2* __restrict__ CC,
                            float* __restrict__ out, int N) {
    int node = blockIdx.x * 4 + (threadIdx.x >> 6);
    int lane = threadIdx.x & 63;
    if (node >= N) return;
    uint hiu = reinterpret_cast<const uint*>(Hnb + (size_t)node * 128)[lane];
    float hix = uasf(hiu << 16), hiy = uasf(hiu & 0xffff0000u);
    int lo = rowptr[node], hiE = rowptr[node + 1];
    float ax = 0.f, ay = 0.f, sc = 0.f;
    for (int e = lo; e < hiE; ++e) {
        int d = dstS[e];
        float2 cc = CC[e];
        uint hju = reinterpret_cast<const uint*>(Hnb + (size_t)d * 128)[lane];
        float hjx = uasf(hju << 16), hjy = uasf(hju & 0xffff0000u);
        ax += cc.x * hjx;
        ay += cc.x * hjy;
        sc += cc.x * cc.y;
    }
    float inv = 1.0f / fmaxf((float)(hiE - lo), 1.0f);
    ax = (ax - sc * hix) * inv;
    ay = (ay - sc * hiy) * inv;
    float ss = ax * ax + ay * ay;
    #pragma unroll
    for (int off = 32; off; off >>= 1) ss += __shfl_xor(ss, off, 64);
    float scale = 1.0f / (sqrtf(ss) + EPS);
    reinterpret_cast<float2*>(out + (size_t)node * 128)[lane] = make_float2(ax * scale, ay * scale);
}

extern "C" void kernel_launch(void* const* d_in, const int* in_sizes, int n_in,
                              void* d_out, int out_size, void* d_ws, size_t ws_size,
                              hipStream_t stream) {
    const float* H    = (const float*)d_in[1];
    const int*   ei   = (const int*)d_in[2];
    const float* w1_1 = (const float*)d_in[3];
    const float* b1_1 = (const float*)d_in[4];
    const float* w1_2 = (const float*)d_in[5];
    const float* b1_2 = (const float*)d_in[6];
    const float* w2_1 = (const float*)d_in[7];
    const float* b2_1 = (const float*)d_in[8];
    const float* w2_2 = (const float*)d_in[9];
    const float* b2_2 = (const float*)d_in[10];

    int N = in_sizes[1] / D;
    int E = in_sizes[2] / 2;
    const int* src = ei;
    const int* dst = ei + E;

    float* out = (float*)d_out;

    // Workspace layout
    short* Hnb  = (short*)d_ws;                   // N*128 bf16
    short* Pb   = Hnb + (size_t)N * D;            // N*128 bf16 (P', later R')
    short* Qb   = Pb + (size_t)N * D;             // N*128 bf16 (Q, later T)
    float* Cb   = (float*)(Qb + (size_t)N * D);   // N*128 fp32
    float2* CC  = (float2*)(Cb + (size_t)N * D);  // E float2 (cur, cos)
    short* Wt   = (short*)(CC + E);               // 5 * 128*128 bf16
    int* deg    = (int*)(Wt + 5 * 16384);         // N
    int* rowptr = deg + N;                        // N+1
    int* fill   = rowptr + N + 1;                 // N
    int* srcS   = fill + N;                       // E
    int* dstS   = srcS + E;                       // E

    hipMemsetAsync(Cb, 0, (size_t)N * D * sizeof(float), stream);
    hipMemsetAsync(deg, 0, (3 * (size_t)N + 1) * sizeof(int), stream);

    k_normalize<<<(N + 3) / 4, 256, 0, stream>>>(H, Hnb, N);
    k_hist<<<1024, 256, 0, stream>>>(src, deg, E);
    k_scan<<<1, 1024, 0, stream>>>(deg, rowptr, N);
    k_scatter<<<1024, 256, 0, stream>>>(src, dst, rowptr, fill, srcS, dstS, E);
    k_prep_all<<<320, 256, 0, stream>>>(w1_1, w1_2, w2_1, Wt);

    k_gemm_dual<true><<<(N + 63) / 64, 256, 0, stream>>>(Hnb, Wt + 0 * 16384, Wt + 1 * 16384,
                                                         b1_1, Pb, Qb, N);
    k_edge_mlp1<<<(E + 63) / 64, 256, 0, stream>>>(srcS, dstS, rowptr, Pb, Qb,
                                                   Wt + 2 * 16384, b1_2, Cb, E);
    k_gemm_dual<false><<<(N + 63) / 64, 256, 0, stream>>>(Cb, Wt + 3 * 16384, Wt + 4 * 16384,
                                                          b2_1, Pb, Qb, N);
    k_edge_scal<<<(E + 15) / 16, 256, 0, stream>>>(srcS, dstS, Hnb, Pb, Qb, w2_2, b2_2, CC, E);
    k_node_curv<<<(N + 3) / 4, 256, 0, stream>>>(dstS, rowptr, Hnb, CC, out, N);
}